// Round 9
// baseline (111.559 us; speedup 1.0000x reference)
//
#include <hip/hip_runtime.h>

// out[b,o,f] = entmax_1.5(0.5 * x[b] @ Q^T)[o,f] * values[o,f]
// B=8192, F=128 (entmax axis), E=64, O=64, fp32 in/out.
//
// R9: = R8 (93.3us) with the Q fp16-hi/lo conversion folded into the main
// kernel (each lane builds its B fragments from fp32 Q in registers; 2x32B
// L2-hot loads + ~80 one-time VALU ops, hidden under x staging latency).
// Removes the convert_q pre-kernel launch + graph serialization gap + d_ws.
// Structure (proven R6/R8): fp16 MFMA 2-product GEMM from swizzled LDS,
// 4-bisection + 3-Newton register solver, block-wide barriered LDS output
// transpose, coalesced NT stores (temporally clustered per block — R7
// showed scattering the NT stream regresses 57%).

typedef __attribute__((ext_vector_type(8))) _Float16 half8;
typedef __attribute__((ext_vector_type(4))) float floatx4;

constexpr int Bn = 8192;

#define NBIS 4
#define NNEWT 3

__device__ inline unsigned pk2(_Float16 a, _Float16 b) {
  union { _Float16 h[2]; unsigned u; } p;
  p.h[0] = a; p.h[1] = b;
  return p.u;
}

__global__ __launch_bounds__(256, 8) void sparse_att_kernel(
    const float* __restrict__ x,      // (B,128,64)
    const float* __restrict__ Qf,     // (64,64) fp32
    const float* __restrict__ vals,   // (64,128)
    float* __restrict__ out)          // (B,64,128)
{
  // 16KB LDS, time-shared: phase 1 = x[b] as fp16 (swizzled, MFMA tile),
  // phase 2 = output transpose staging (2 passes of 64x64 f32).
  __shared__ __align__(16) unsigned char ldsbuf[16384];
  _Float16* xh = (_Float16*)ldsbuf;

  const int b   = blockIdx.x;
  const int tid = threadIdx.x;
  const int l   = tid & 63;
  const int otile = tid >> 6;         // wave id 0..3 -> o-tile
  const int lc  = l & 15;             // A-row within tile / C-col (o)
  const int fq  = l >> 4;             // k-block selector / C row-quad
  const int o   = otile * 16 + lc;    // this lane's output o (C layout)

  // ---- stage x[b] -> LDS fp16 hi, swizzled ----
  {
    const float4* xg = (const float4*)(x + (size_t)b * 8192);
    #pragma unroll
    for (int k = 0; k < 8; ++k) {
      int j = tid + k * 256;          // float4 index 0..2047
      int f = j >> 4, c = j & 15;
      float4 v = xg[j];
      _Float16 h0 = (_Float16)v.x, h1 = (_Float16)v.y,
               h2 = (_Float16)v.z, h3 = (_Float16)v.w;
      int byteoff = f * 128 + (((c >> 1) ^ (f & 7)) * 16) + (c & 1) * 8;
      uint2 uh; uh.x = pk2(h0, h1); uh.y = pk2(h2, h3);
      *(uint2*)((char*)xh + byteoff) = uh;
    }
  }

  // ---- B fragments: 0.5*Q[o][k] split hi/lo in-register (L2-hot reads) --
  // B layout: lane holds B[k = ks*32 + fq*8 .. +7][n = lc].
  half8 bh0, bh1, bl0, bl1;
  {
    const float* qrow = Qf + o * 64;
    #pragma unroll
    for (int ks = 0; ks < 2; ++ks) {
      float4 qa = *(const float4*)(qrow + ks * 32 + fq * 8);
      float4 qb = *(const float4*)(qrow + ks * 32 + fq * 8 + 4);
      float qs0 = qa.x * 0.5f, qs1 = qa.y * 0.5f,
            qs2 = qa.z * 0.5f, qs3 = qa.w * 0.5f,
            qs4 = qb.x * 0.5f, qs5 = qb.y * 0.5f,
            qs6 = qb.z * 0.5f, qs7 = qb.w * 0.5f;
      half8 h, lo;
      h[0] = (_Float16)qs0; lo[0] = (_Float16)(qs0 - (float)h[0]);
      h[1] = (_Float16)qs1; lo[1] = (_Float16)(qs1 - (float)h[1]);
      h[2] = (_Float16)qs2; lo[2] = (_Float16)(qs2 - (float)h[2]);
      h[3] = (_Float16)qs3; lo[3] = (_Float16)(qs3 - (float)h[3]);
      h[4] = (_Float16)qs4; lo[4] = (_Float16)(qs4 - (float)h[4]);
      h[5] = (_Float16)qs5; lo[5] = (_Float16)(qs5 - (float)h[5]);
      h[6] = (_Float16)qs6; lo[6] = (_Float16)(qs6 - (float)h[6]);
      h[7] = (_Float16)qs7; lo[7] = (_Float16)(qs7 - (float)h[7]);
      if (ks == 0) { bh0 = h; bl0 = lo; } else { bh1 = h; bl1 = lo; }
    }
  }

  __syncthreads();

  // ---- GEMM: C[f][o] tiles via mfma_f32_16x16x32_f16, 2-product split ----
  floatx4 acc[8];
  #pragma unroll
  for (int t = 0; t < 8; ++t) acc[t] = (floatx4)0.0f;

  #pragma unroll
  for (int ks = 0; ks < 2; ++ks) {
    half8 bh = ks ? bh1 : bh0;
    half8 bl = ks ? bl1 : bl0;
    #pragma unroll
    for (int ft = 0; ft < 8; ++ft) {
      int f = ft * 16 + lc;                    // A-row for this lane
      int blk = (ks * 4 + fq) ^ (f & 7);
      int byteoff = f * 128 + blk * 16;
      half8 ah = *(const half8*)((const char*)xh + byteoff);
      acc[ft] = __builtin_amdgcn_mfma_f32_16x16x32_f16(ah, bh, acc[ft], 0, 0, 0);
      acc[ft] = __builtin_amdgcn_mfma_f32_16x16x32_f16(ah, bl, acc[ft], 0, 0, 0);
    }
  }

  // ---- att = Xs (0.5 folded into Q); lane's f for acc[t][j] = t*16+fq*4+j
  float* att = (float*)acc;                    // 32 floats, static indexing

  // ---- row max over 128 f (4 lanes: xor 16, 32) ----
  float m = att[0];
  #pragma unroll
  for (int i = 1; i < 32; ++i) m = fmaxf(m, att[i]);
  m = fmaxf(m, __shfl_xor(m, 16));
  m = fmaxf(m, __shfl_xor(m, 32));

  // ---- bisection (keeps f(tau) >= 0 invariant) ----
  float tau = m - 1.0f;
  float dm  = 0.91161165235168155f;       // 1 - (1/128)^0.5
  #pragma unroll
  for (int it = 0; it < NBIS; ++it) {
    dm *= 0.5f;
    float tm = tau + dm;
    float s0 = 0.f, s1 = 0.f, s2 = 0.f, s3 = 0.f;
    #pragma unroll
    for (int i = 0; i < 32; i += 4) {
      float t0 = fmaxf(att[i + 0] - tm, 0.0f);
      float t1 = fmaxf(att[i + 1] - tm, 0.0f);
      float t2 = fmaxf(att[i + 2] - tm, 0.0f);
      float t3 = fmaxf(att[i + 3] - tm, 0.0f);
      s0 = fmaf(t0, t0, s0); s1 = fmaf(t1, t1, s1);
      s2 = fmaf(t2, t2, s2); s3 = fmaf(t3, t3, s3);
    }
    float s = (s0 + s1) + (s2 + s3);
    s += __shfl_xor(s, 16);
    s += __shfl_xor(s, 32);
    tau = (s >= 1.0f) ? tm : tau;
  }

  // ---- Newton (monotone from f>=0 side; f convex, never overshoots) ----
  #pragma unroll
  for (int it = 0; it < NNEWT; ++it) {
    float s0 = 0.f, s1 = 0.f, d0 = 0.f, d1 = 0.f;
    #pragma unroll
    for (int i = 0; i < 32; i += 2) {
      float t0 = fmaxf(att[i + 0] - tau, 0.0f);
      float t1 = fmaxf(att[i + 1] - tau, 0.0f);
      s0 = fmaf(t0, t0, s0); d0 += t0;
      s1 = fmaf(t1, t1, s1); d1 += t1;
    }
    float s = s0 + s1, d = d0 + d1;
    s += __shfl_xor(s, 16);  d += __shfl_xor(d, 16);
    s += __shfl_xor(s, 32);  d += __shfl_xor(d, 32);
    tau += (s - 1.0f) / (2.0f * d);
  }

  // ---- final p and sum ----
  float s0 = 0.f, s1 = 0.f;
  #pragma unroll
  for (int i = 0; i < 32; ++i) {
    float t = fmaxf(att[i] - tau, 0.0f);
    float p = t * t;
    att[i] = p;
    if (i & 1) s1 += p; else s0 += p;
  }
  float s = s0 + s1;
  s += __shfl_xor(s, 16);
  s += __shfl_xor(s, 32);
  float inv = 1.0f / s;

  // ---- epilogue: p*inv*vals, transposed through LDS, coalesced NT store
  const float4* vg = (const float4*)(vals + o * 128);
  #pragma unroll
  for (int pass = 0; pass < 2; ++pass) {
    __syncthreads();   // pass0: all waves done reading x-tile; pass1: pass0 reads done
    #pragma unroll
    for (int t = 0; t < 4; ++t) {
      int ft = pass * 4 + t;
      float4 vv = vg[ft * 4 + fq];           // vals[o][ft*16+fq*4 .. +3]
      floatx4 r;
      r.x = att[ft * 4 + 0] * inv * vv.x;
      r.y = att[ft * 4 + 1] * inv * vv.y;
      r.z = att[ft * 4 + 2] * inv * vv.z;
      r.w = att[ft * 4 + 3] * inv * vv.w;
      int fr = ft * 16 + fq * 4 - pass * 64; // 0..63 f-local to this pass
      int off = (o * 256 + fr * 4) ^ ((o & 7) << 4);
      *(floatx4*)(ldsbuf + off) = r;
    }
    __syncthreads();
    #pragma unroll
    for (int k = 0; k < 4; ++k) {
      int j = tid + k * 256;                 // float4 index 0..1023
      int oo = j >> 4, f4 = j & 15;
      int off = (oo * 256 + f4 * 16) ^ ((oo & 7) << 4);
      floatx4 r = *(const floatx4*)(ldsbuf + off);
      __builtin_nontemporal_store(
          r, (floatx4*)(out + ((size_t)b * 64 + oo) * 128 + pass * 64 + f4 * 4));
    }
  }
}

extern "C" void kernel_launch(void* const* d_in, const int* in_sizes, int n_in,
                              void* d_out, int out_size, void* d_ws, size_t ws_size,
                              hipStream_t stream) {
  const float* x  = (const float*)d_in[0];
  const float* Qf = (const float*)d_in[1];
  const float* v  = (const float*)d_in[2];
  float* out = (float*)d_out;

  hipLaunchKernelGGL(sparse_att_kernel, dim3(Bn), dim3(256), 0, stream,
                     x, Qf, v, out);
}

// Round 10
// 92.629 us; speedup vs baseline: 1.2044x; 1.2044x over previous
//
#include <hip/hip_runtime.h>

// out[b,o,f] = entmax_1.5(0.5 * x[b] @ Q^T)[o,f] * values[o,f]
// B=8192, F=128 (entmax axis), E=64, O=64, fp32 in/out.
//
// R10: exact revert to R8 (93.3us known-good). R9 (fold Q-convert into the
// main kernel) REGRESSED to 111.6us: the pre-kernel was graph-overlapped
// (free), and the in-kernel conversion put ~100 VALU ops + fp32 Q loads on
// the pre-barrier critical path of all 8192 blocks. Keep the two-kernel
// structure: tiny convert_q writes fp16 hi/lo of 0.5*Q to d_ws; main
// kernel loads B fragments lazily (drain after barrier, latency hidden).
//
// Proven structure (R6/R8): fp16 MFMA 2-product GEMM from XOR-swizzled
// LDS, 4-bisection + 3-Newton register solver (absmax floored at bf16
// ulp), block-wide barriered LDS output transpose, coalesced NT stores
// temporally clustered per block (R7: scattering the NT stream = -57%).

typedef __attribute__((ext_vector_type(8))) _Float16 half8;
typedef __attribute__((ext_vector_type(4))) float floatx4;

constexpr int Bn = 8192;

#define NBIS 4
#define NNEWT 3

// ---- pre-kernel: 0.5*Q (64x64 f32) -> fp16 hi/lo in workspace ----
__global__ void convert_q_kernel(const float* __restrict__ Qf,
                                 _Float16* __restrict__ Qh,
                                 _Float16* __restrict__ Ql) {
  int i = blockIdx.x * 256 + threadIdx.x;   // 4096 elements
  float q = Qf[i] * 0.5f;                   // fold alpha-1 here
  _Float16 h = (_Float16)q;
  float r = q - (float)h;
  Qh[i] = h;
  Ql[i] = (_Float16)r;
}

__device__ inline unsigned pk2(_Float16 a, _Float16 b) {
  union { _Float16 h[2]; unsigned u; } p;
  p.h[0] = a; p.h[1] = b;
  return p.u;
}

__global__ __launch_bounds__(256, 8) void sparse_att_kernel(
    const float* __restrict__ x,      // (B,128,64)
    const _Float16* __restrict__ Qh,  // (64,64) fp16 hi of 0.5*Q
    const _Float16* __restrict__ Ql,  // (64,64) fp16 lo of 0.5*Q
    const float* __restrict__ vals,   // (64,128)
    float* __restrict__ out)          // (B,64,128)
{
  // 16KB LDS, time-shared: phase 1 = x[b] as fp16 (swizzled, MFMA tile),
  // phase 2 = output transpose staging (2 passes of 64x64 f32).
  __shared__ __align__(16) unsigned char ldsbuf[16384];
  _Float16* xh = (_Float16*)ldsbuf;

  const int b   = blockIdx.x;
  const int tid = threadIdx.x;
  const int l   = tid & 63;
  const int otile = tid >> 6;         // wave id 0..3 -> o-tile
  const int lc  = l & 15;             // A-row within tile / C-col (o)
  const int fq  = l >> 4;             // k-block selector / C row-quad
  const int o   = otile * 16 + lc;    // this lane's output o (C layout)

  // ---- stage x[b] -> LDS fp16 hi, swizzled ----
  {
    const float4* xg = (const float4*)(x + (size_t)b * 8192);
    #pragma unroll
    for (int k = 0; k < 8; ++k) {
      int j = tid + k * 256;          // float4 index 0..2047
      int f = j >> 4, c = j & 15;
      float4 v = xg[j];
      _Float16 h0 = (_Float16)v.x, h1 = (_Float16)v.y,
               h2 = (_Float16)v.z, h3 = (_Float16)v.w;
      int byteoff = f * 128 + (((c >> 1) ^ (f & 7)) * 16) + (c & 1) * 8;
      uint2 uh; uh.x = pk2(h0, h1); uh.y = pk2(h2, h3);
      *(uint2*)((char*)xh + byteoff) = uh;
    }
  }

  // ---- B fragments (0.5*Q hi/lo) straight from global (L2-hot, 16KB) ----
  half8 bh0 = *(const half8*)(Qh + o * 64 + 0 * 32 + fq * 8);
  half8 bh1 = *(const half8*)(Qh + o * 64 + 1 * 32 + fq * 8);
  half8 bl0 = *(const half8*)(Ql + o * 64 + 0 * 32 + fq * 8);
  half8 bl1 = *(const half8*)(Ql + o * 64 + 1 * 32 + fq * 8);

  __syncthreads();

  // ---- GEMM: C[f][o] tiles via mfma_f32_16x16x32_f16, 2-product split ----
  floatx4 acc[8];
  #pragma unroll
  for (int t = 0; t < 8; ++t) acc[t] = (floatx4)0.0f;

  #pragma unroll
  for (int ks = 0; ks < 2; ++ks) {
    half8 bh = ks ? bh1 : bh0;
    half8 bl = ks ? bl1 : bl0;
    #pragma unroll
    for (int ft = 0; ft < 8; ++ft) {
      int f = ft * 16 + lc;                    // A-row for this lane
      int blk = (ks * 4 + fq) ^ (f & 7);
      int byteoff = f * 128 + blk * 16;
      half8 ah = *(const half8*)((const char*)xh + byteoff);
      acc[ft] = __builtin_amdgcn_mfma_f32_16x16x32_f16(ah, bh, acc[ft], 0, 0, 0);
      acc[ft] = __builtin_amdgcn_mfma_f32_16x16x32_f16(ah, bl, acc[ft], 0, 0, 0);
    }
  }

  // ---- att = Xs (0.5 folded into Q); lane's f for acc[t][j] = t*16+fq*4+j
  float* att = (float*)acc;                    // 32 floats, static indexing

  // ---- row max over 128 f (4 lanes: xor 16, 32) ----
  float m = att[0];
  #pragma unroll
  for (int i = 1; i < 32; ++i) m = fmaxf(m, att[i]);
  m = fmaxf(m, __shfl_xor(m, 16));
  m = fmaxf(m, __shfl_xor(m, 32));

  // ---- bisection (keeps f(tau) >= 0 invariant) ----
  float tau = m - 1.0f;
  float dm  = 0.91161165235168155f;       // 1 - (1/128)^0.5
  #pragma unroll
  for (int it = 0; it < NBIS; ++it) {
    dm *= 0.5f;
    float tm = tau + dm;
    float s0 = 0.f, s1 = 0.f, s2 = 0.f, s3 = 0.f;
    #pragma unroll
    for (int i = 0; i < 32; i += 4) {
      float t0 = fmaxf(att[i + 0] - tm, 0.0f);
      float t1 = fmaxf(att[i + 1] - tm, 0.0f);
      float t2 = fmaxf(att[i + 2] - tm, 0.0f);
      float t3 = fmaxf(att[i + 3] - tm, 0.0f);
      s0 = fmaf(t0, t0, s0); s1 = fmaf(t1, t1, s1);
      s2 = fmaf(t2, t2, s2); s3 = fmaf(t3, t3, s3);
    }
    float s = (s0 + s1) + (s2 + s3);
    s += __shfl_xor(s, 16);
    s += __shfl_xor(s, 32);
    tau = (s >= 1.0f) ? tm : tau;
  }

  // ---- Newton (monotone from f>=0 side; f convex, never overshoots) ----
  #pragma unroll
  for (int it = 0; it < NNEWT; ++it) {
    float s0 = 0.f, s1 = 0.f, d0 = 0.f, d1 = 0.f;
    #pragma unroll
    for (int i = 0; i < 32; i += 2) {
      float t0 = fmaxf(att[i + 0] - tau, 0.0f);
      float t1 = fmaxf(att[i + 1] - tau, 0.0f);
      s0 = fmaf(t0, t0, s0); d0 += t0;
      s1 = fmaf(t1, t1, s1); d1 += t1;
    }
    float s = s0 + s1, d = d0 + d1;
    s += __shfl_xor(s, 16);  d += __shfl_xor(d, 16);
    s += __shfl_xor(s, 32);  d += __shfl_xor(d, 32);
    tau += (s - 1.0f) / (2.0f * d);
  }

  // ---- final p and sum ----
  float s0 = 0.f, s1 = 0.f;
  #pragma unroll
  for (int i = 0; i < 32; ++i) {
    float t = fmaxf(att[i] - tau, 0.0f);
    float p = t * t;
    att[i] = p;
    if (i & 1) s1 += p; else s0 += p;
  }
  float s = s0 + s1;
  s += __shfl_xor(s, 16);
  s += __shfl_xor(s, 32);
  float inv = 1.0f / s;

  // ---- epilogue: p*inv*vals, transposed through LDS, coalesced NT store
  const float4* vg = (const float4*)(vals + o * 128);
  #pragma unroll
  for (int pass = 0; pass < 2; ++pass) {
    __syncthreads();   // pass0: all waves done reading x-tile; pass1: pass0 reads done
    #pragma unroll
    for (int t = 0; t < 4; ++t) {
      int ft = pass * 4 + t;
      float4 vv = vg[ft * 4 + fq];           // vals[o][ft*16+fq*4 .. +3]
      floatx4 r;
      r.x = att[ft * 4 + 0] * inv * vv.x;
      r.y = att[ft * 4 + 1] * inv * vv.y;
      r.z = att[ft * 4 + 2] * inv * vv.z;
      r.w = att[ft * 4 + 3] * inv * vv.w;
      int fr = ft * 16 + fq * 4 - pass * 64; // 0..63 f-local to this pass
      int off = (o * 256 + fr * 4) ^ ((o & 7) << 4);
      *(floatx4*)(ldsbuf + off) = r;
    }
    __syncthreads();
    #pragma unroll
    for (int k = 0; k < 4; ++k) {
      int j = tid + k * 256;                 // float4 index 0..1023
      int oo = j >> 4, f4 = j & 15;
      int off = (oo * 256 + f4 * 16) ^ ((oo & 7) << 4);
      floatx4 r = *(const floatx4*)(ldsbuf + off);
      __builtin_nontemporal_store(
          r, (floatx4*)(out + ((size_t)b * 64 + oo) * 128 + pass * 64 + f4 * 4));
    }
  }
}

extern "C" void kernel_launch(void* const* d_in, const int* in_sizes, int n_in,
                              void* d_out, int out_size, void* d_ws, size_t ws_size,
                              hipStream_t stream) {
  const float* x  = (const float*)d_in[0];
  const float* Qf = (const float*)d_in[1];
  const float* v  = (const float*)d_in[2];
  float* out = (float*)d_out;

  _Float16* Qh = (_Float16*)d_ws;            // 4096 halves = 8KB
  _Float16* Ql = Qh + 4096;                  // next 8KB

  hipLaunchKernelGGL(convert_q_kernel, dim3(16), dim3(256), 0, stream, Qf, Qh, Ql);
  hipLaunchKernelGGL(sparse_att_kernel, dim3(Bn), dim3(256), 0, stream,
                     x, Qh, Ql, v, out);
}